// Round 7
// baseline (85.888 us; speedup 1.0000x reference)
//
#include <hip/hip_runtime.h>
#include <hip/hip_bf16.h>
#include <math.h>

#define BB 4
#define CC 256
#define HH 128
#define WW 128
#define NN (HH*WW)
#define DD 32

// AOT: attention output, bf16, spatially padded +1 border, ci padded 32->44.
#define AOT_CI   44
#define AOT_ROWE (130*AOT_CI)                  // shorts per padded row (5720)
#define AOT_IMGE (130*AOT_ROWE)                // shorts per batch (743600)
#define AOT_BYTES ((size_t)BB*AOT_IMGE*2)      // 5,948,800
#define AOT_ALLOC (AOT_BYTES + 1024)

#define WT_BYTES (9*256*AOT_CI*2)              // 202,752

// conv LDS geometry (2-row tile, unchanged from round 5/6)
#define PATCH_SZ 45760                         // 4 padded rows * 130 * 88
#define WSLAB    22528                         // 256 co * 88
#define CONV_LDS (PATCH_SZ + 2*WSLAB)          // 90,816
#define EPI_PITCH 260

// qkv: A pre-swizzled [32 kstep][3 cf][64 lane][8 bf16] = 96 KB, staged in
// two 48 KB halves.
#define ASWZ_BYTES 98304
#define AHALF      49152
#define QK2        132                         // epilogue qk row pitch (floats)

typedef __attribute__((ext_vector_type(8)))  short bf16x8;
typedef __attribute__((ext_vector_type(4)))  float f32x4;
typedef __attribute__((ext_vector_type(16))) float f32x16;

__device__ inline void async_copy16(void* lds, const void* g) {
    __builtin_amdgcn_global_load_lds(
        (const __attribute__((address_space(1))) unsigned int*)g,
        (__attribute__((address_space(3))) unsigned int*)lds, 16, 0, 0);
}

__device__ inline unsigned short f2bf(float f) {
    __hip_bfloat16 h = __float2bfloat16(f);
    return *reinterpret_cast<unsigned short*>(&h);
}

__device__ inline void split2(float v, unsigned short& h, unsigned short& l) {
    __hip_bfloat16 hb = __float2bfloat16(v);
    float r = v - __bfloat162float(hb);     // exact (Sterbenz)
    __hip_bfloat16 lb = __float2bfloat16(r);
    h = *reinterpret_cast<unsigned short*>(&hb);
    l = *reinterpret_cast<unsigned short*>(&lb);
}

// 8B+8B LDS load of a bf16x8 fragment (88B row pitch is only 8B-aligned)
__device__ inline bf16x8 ld_frag8(const char* p) {
    union { bf16x8 v; short4 h[2]; } u;
    u.h[0] = *(const short4*)(p);
    u.h[1] = *(const short4*)(p + 8);
    return u.v;
}

// A&S 7.1.26 erf approximation, |err| ~1e-6
__device__ inline float gelu_fast(float v) {
    float a = fabsf(v) * 0.70710678118654752f;
    float t = __fdividef(1.0f, fmaf(0.3275911f, a, 1.0f));
    float p = t * fmaf(t, fmaf(t, fmaf(t, fmaf(t, 1.061405429f, -1.453152027f),
                                       1.421413741f), -0.284496736f), 0.254829592f);
    float e = 1.0f - p * __expf(-a * a);
    float erfv = (v < 0.0f) ? -e : e;
    return 0.5f * v * (1.0f + erfv);
}

// ---------------------------------------------------------------------------
// K0: fused prep — conv weight repack | qkv A-pack | AOT border zero.
// grid 1024 x 256: blocks [0,288) wrepack, [288,480) wrepack2, [480,...) zero.
// ---------------------------------------------------------------------------
__global__ __launch_bounds__(256) void prep_kernel(
    const float* __restrict__ wp, unsigned short* __restrict__ Wt,
    const float* __restrict__ wq, const float* __restrict__ wk,
    const float* __restrict__ wv, unsigned short* __restrict__ Aswz,
    unsigned short* __restrict__ AOT)
{
    const int blk = blockIdx.x;
    if (blk < 288) {                       // conv weights: 9*256*32 = 73728
        int i = blk*256 + threadIdx.x;
        int kk = i / (256*32);
        int r  = i % (256*32);
        int co = r >> 5, ci = r & 31;
        float v = wp[((size_t)co*32 + ci)*9 + kk];
        Wt[((size_t)kk*256 + co)*AOT_CI + ci] = f2bf(v);
    } else if (blk < 480) {                // qkv A image: 49152 entries
        int i = (blk-288)*256 + threadIdx.x;
        int j    = i & 7;
        int lane = (i >> 3) & 63;
        int cf   = (i >> 9) % 3;
        int s    = i / 1536;
        int row  = cf*32 + (lane & 31);
        int k    = s*16 + (lane >> 5)*8 + j;
        int c    = k >> 1;
        float w  = (row < 32) ? wq[row*256 + c]
                 : (row < 64) ? wk[(row-32)*256 + c]
                              : wv[(row-64)*256 + c];
        unsigned short h, l;
        split2(w, h, l);
        Aswz[i] = (k & 1) ? l : h;
    } else {                               // AOT border zero: 4*22704 shorts
        int idx = (blk-480)*256 + threadIdx.x;
        if (idx < BB*22704) {
            int b = idx / 22704;
            int r = idx % 22704;
            size_t off;
            if (r < 11440) {               // padded rows 0 and 129, full
                int row = (r < 5720) ? 0 : 129;
                int e   = (r < 5720) ? r : r - 5720;
                off = (size_t)b*AOT_IMGE + (size_t)row*AOT_ROWE + e;
            } else {                       // rows 1..128, cols 0 and 129
                int r2 = r - 11440;
                int rr = r2 / 88 + 1;
                int w2 = r2 % 88;
                int col = (w2 < 44) ? 0 : 129;
                int ci  = (w2 < 44) ? w2 : w2 - 44;
                off = (size_t)b*AOT_IMGE + (size_t)rr*AOT_ROWE
                    + (size_t)col*AOT_CI + ci;
            }
            AOT[off] = 0;
        }
    }
}

// ---------------------------------------------------------------------------
// K1: QKV streaming MFMA GEMM + fused energy partial.
// grid (128 n-tiles, B), 256 thr = 4 waves; wave w owns n-cols [32w, 32w+32).
// A staged in two 48 KB halves (restage mid-loop) -> LDS 49.5 KB, 2 blocks/CU.
// x loaded straight to registers (4-step queue), truncation-split to (hi,lo),
// MFMA 32x32x16: acc += A*(xh dup) + A*(xl dup)  (A k-slots = [w_hi, w_lo]).
// Epilogue: Q,K(+bias) -> LDS (reuse A region), V(+bias) -> global, then
// 32x32 energy partial over this block's 128 n.
// ---------------------------------------------------------------------------
__global__ __launch_bounds__(256, 4) void qkv_mfma_kernel(
    const float* __restrict__ x, const unsigned short* __restrict__ Aswz,
    const float* __restrict__ bq, const float* __restrict__ bk,
    const float* __restrict__ bv,
    float* __restrict__ Vout, float* __restrict__ Ep)
{
    __shared__ __align__(16) char lds[AHALF];        // A half, reused for QK
    __shared__ float biasL[96];
    const int b    = blockIdx.y;
    const int s    = blockIdx.x;
    const int n0   = s * 128;
    const int tid  = threadIdx.x;
    const int lane = tid & 63;
    const int wid  = tid >> 6;                       // 0..3
    const int l31  = lane & 31;
    const int lh   = lane >> 5;
    const int nloc = 32*wid + l31;                   // 0..127

    // stage A half 0 (48 KB linear)
    for (int i = tid; i < 3072; i += 256)
        async_copy16(lds + i*16, (const char*)Aswz + i*16);
    if (tid < 96)
        biasL[tid] = (tid < 32) ? bq[tid] : (tid < 64) ? bk[tid-32] : bv[tid-64];

    const float* xlane = x + ((size_t)b*CC + 4*lh)*NN + (n0 + nloc);

    f32x16 acc0 = {0}, acc1 = {0}, acc2 = {0};

    float xq[4][4];
    #pragma unroll
    for (int p0 = 0; p0 < 4; ++p0) {
        const float* p = xlane + (size_t)(8*p0)*NN;
        xq[p0][0] = p[0];            xq[p0][1] = p[(size_t)NN];
        xq[p0][2] = p[(size_t)2*NN]; xq[p0][3] = p[(size_t)3*NN];
    }

    auto run_half = [&](int st_base) {
        for (int su = 0; su < 16; su += 4) {
            #pragma unroll
            for (int ph = 0; ph < 4; ++ph) {
                const int stl = su + ph;             // lds-local step
                const int st  = st_base + stl;       // global step
                const char* ab = lds + (size_t)(stl*3)*1024 + lane*16;
                bf16x8 a0 = *(const bf16x8*)(ab);
                bf16x8 a1 = *(const bf16x8*)(ab + 1024);
                bf16x8 a2 = *(const bf16x8*)(ab + 2048);
                float v0 = xq[ph][0], v1 = xq[ph][1];
                float v2 = xq[ph][2], v3 = xq[ph][3];
                if (st + 4 < 32) {
                    const float* p = xlane + (size_t)(8*(st+4))*NN;
                    xq[ph][0] = p[0];            xq[ph][1] = p[(size_t)NN];
                    xq[ph][2] = p[(size_t)2*NN]; xq[ph][3] = p[(size_t)3*NN];
                }
                // truncation split: hi = bits&0xFFFF0000, lo = trunc16(v-hi)
                union { bf16x8 v; unsigned int u[4]; } B1, B2;
                #pragma unroll
                for (int j = 0; j < 4; ++j) {
                    float vj = (j==0)?v0:(j==1)?v1:(j==2)?v2:v3;
                    unsigned int hb = __float_as_uint(vj) & 0xFFFF0000u;
                    float rj = vj - __uint_as_float(hb);
                    unsigned int lb = __float_as_uint(rj) >> 16;
                    B1.u[j] = hb | (hb >> 16);
                    B2.u[j] = lb | (lb << 16);
                }
                acc0 = __builtin_amdgcn_mfma_f32_32x32x16_bf16(a0, B1.v, acc0, 0, 0, 0);
                acc1 = __builtin_amdgcn_mfma_f32_32x32x16_bf16(a1, B1.v, acc1, 0, 0, 0);
                acc2 = __builtin_amdgcn_mfma_f32_32x32x16_bf16(a2, B1.v, acc2, 0, 0, 0);
                acc0 = __builtin_amdgcn_mfma_f32_32x32x16_bf16(a0, B2.v, acc0, 0, 0, 0);
                acc1 = __builtin_amdgcn_mfma_f32_32x32x16_bf16(a1, B2.v, acc1, 0, 0, 0);
                acc2 = __builtin_amdgcn_mfma_f32_32x32x16_bf16(a2, B2.v, acc2, 0, 0, 0);
            }
        }
    };

    __syncthreads();                     // A half0 resident
    run_half(0);
    __syncthreads();                     // all waves done reading half0
    for (int i = tid; i < 3072; i += 256)
        async_copy16(lds + i*16, (const char*)Aswz + AHALF + i*16);
    __syncthreads();                     // half1 resident
    run_half(16);

    // ---- epilogue: Q,K -> LDS (+bias), V -> global (+bias) ----
    __syncthreads();
    float* qk = (float*)lds;             // [64 rows][QK2]
    #pragma unroll
    for (int r = 0; r < 16; ++r) {
        const int rsub = (r & 3) + 8*(r >> 2) + 4*lh;    // 0..31
        qk[rsub*QK2 + nloc]      = acc0[r] + biasL[rsub];
        qk[(32+rsub)*QK2 + nloc] = acc1[r] + biasL[32+rsub];
        Vout[((size_t)b*DD + rsub)*NN + n0 + nloc] = acc2[r] + biasL[64+rsub];
    }
    __syncthreads();

    // ---- energy partial: E[d][e] = sum_n Q[d][n]*K[e][n] over 128 n ----
    const int d  = tid >> 3;             // 0..31
    const int e0 = tid & 7;              // 0..7; handles e0, e0+8, e0+16, e0+24
    const float* qrow = qk + d*QK2;
    float s0 = 0.f, s1 = 0.f, s2 = 0.f, s3 = 0.f;
    for (int n4 = 0; n4 < 128; n4 += 4) {
        float4 qv = *(const float4*)(qrow + n4);
        float4 k0 = *(const float4*)(qk + (32 + e0     )*QK2 + n4);
        float4 k1 = *(const float4*)(qk + (32 + e0 +  8)*QK2 + n4);
        float4 k2 = *(const float4*)(qk + (32 + e0 + 16)*QK2 + n4);
        float4 k3 = *(const float4*)(qk + (32 + e0 + 24)*QK2 + n4);
        s0 += qv.x*k0.x + qv.y*k0.y + qv.z*k0.z + qv.w*k0.w;
        s1 += qv.x*k1.x + qv.y*k1.y + qv.z*k1.z + qv.w*k1.w;
        s2 += qv.x*k2.x + qv.y*k2.y + qv.z*k2.z + qv.w*k2.w;
        s3 += qv.x*k3.x + qv.y*k3.y + qv.z*k3.z + qv.w*k3.w;
    }
    float* ep = Ep + ((size_t)s*BB + b)*1024;
    ep[d*32 + e0]      = s0;
    ep[d*32 + e0 + 8]  = s1;
    ep[d*32 + e0 + 16] = s2;
    ep[d*32 + e0 + 24] = s3;
}

// ---------------------------------------------------------------------------
// K3: softmax over 128 partials.  softmax(max-E)==softmax(-E).
// ---------------------------------------------------------------------------
__global__ __launch_bounds__(1024) void softmax_kernel(
    const float* __restrict__ Ep, float* __restrict__ attT)
{
    const int b = blockIdx.x;
    const int e = threadIdx.x, d = threadIdx.y;
    float s = 0.f;
    for (int p = 0; p < 128; ++p)
        s += Ep[((size_t)p * BB + b) * (DD * DD) + d * DD + e];
    float nv = -s;
    float m = nv;
    for (int off = 16; off > 0; off >>= 1) m = fmaxf(m, __shfl_xor(m, off, 32));
    float pe = expf(nv - m);
    float su = pe;
    for (int off = 16; off > 0; off >>= 1) su += __shfl_xor(su, off, 32);
    attT[(size_t)b * (DD * DD) + e * DD + d] = pe / su;
}

// ---------------------------------------------------------------------------
// K4: PV — 128-n blocks (grid 512, 2+ blocks/CU), d split across thread
// halves; float4 V staging; writes bf16 AOT padded layout.
// ---------------------------------------------------------------------------
__global__ __launch_bounds__(256) void pv_kernel(
    const float* __restrict__ V, const float* __restrict__ attT,
    unsigned short* __restrict__ AOT)
{
    __shared__ float Vs[DD][128];
    __shared__ float at4[DD][DD];        // [e][d]
    const int b  = blockIdx.y;
    const int n0 = blockIdx.x * 128;
    const int tid = threadIdx.x;
    for (int i = tid; i < 1024; i += 256) {
        int r = i >> 5, c4 = i & 31;
        *(float4*)&Vs[r][c4*4] =
            *(const float4*)(V + ((size_t)b*DD + r)*NN + n0 + c4*4);
    }
    for (int i = tid; i < 1024; i += 256)
        at4[i >> 5][i & 31] = attT[(size_t)b*1024 + i];
    __syncthreads();
    const int nl = tid & 127;
    const int dg = tid >> 7;             // 0/1 -> d range dg*16..dg*16+15
    float acc[16];
    #pragma unroll
    for (int k = 0; k < 16; ++k) acc[k] = 0.f;
    #pragma unroll 4
    for (int e = 0; e < DD; ++e) {
        float v = Vs[e][nl];
        const float4* ar = (const float4*)&at4[e][dg*16];
        #pragma unroll
        for (int q = 0; q < 4; ++q) {
            float4 a = ar[q];
            acc[4*q+0] += a.x * v; acc[4*q+1] += a.y * v;
            acc[4*q+2] += a.z * v; acc[4*q+3] += a.w * v;
        }
    }
    const int n = n0 + nl;
    const int h = n >> 7, w = n & 127;
    unsigned short* dst = AOT + (size_t)b*AOT_IMGE + (size_t)(h+1)*AOT_ROWE
                              + (size_t)(w+1)*AOT_CI + dg*16;
    #pragma unroll
    for (int q = 0; q < 4; ++q) {
        ushort4 u;
        u.x = f2bf(acc[4*q+0]); u.y = f2bf(acc[4*q+1]);
        u.z = f2bf(acc[4*q+2]); u.w = f2bf(acc[4*q+3]);
        *(ushort4*)(dst + 4*q) = u;
    }
}

// ---------------------------------------------------------------------------
// K5: conv implicit-GEMM, 2 H-rows per block (unchanged from round 5/6).
// ---------------------------------------------------------------------------
__global__ __launch_bounds__(512, 1) void conv_kernel(
    const unsigned short* __restrict__ AOT, const unsigned short* __restrict__ Wt,
    const float* __restrict__ gammap, const float* __restrict__ x,
    float* __restrict__ out)
{
    __shared__ __align__(16) char lds[CONV_LDS];
    const int b   = blockIdx.y;
    const int h0  = blockIdx.x * 2;
    const int tid = threadIdx.x;
    const int wid = tid >> 6;
    const int lane = tid & 63;
    const int l15 = lane & 15;
    const int lj  = lane >> 4;
    const int wn  = wid & 1;
    const int wc  = wid >> 1;

    const char* psrc = (const char*)(AOT + (size_t)b*AOT_IMGE + (size_t)h0*AOT_ROWE);
    for (int i = tid; i < PATCH_SZ/16; i += 512)
        async_copy16(lds + i*16, psrc + i*16);
    for (int i = tid; i < WSLAB/16; i += 512)
        async_copy16(lds + PATCH_SZ + i*16, (const char*)Wt + i*16);
    __syncthreads();

    f32x4 acc[4][8];
    #pragma unroll
    for (int cf = 0; cf < 4; ++cf)
        #pragma unroll
        for (int nf = 0; nf < 8; ++nf)
            acc[cf][nf] = (f32x4){0.f, 0.f, 0.f, 0.f};

    for (int kk = 0; kk < 9; ++kk) {
        if (kk < 8) {
            const char* wsrc = (const char*)Wt + (size_t)(kk+1)*WSLAB;
            char* wdst = lds + PATCH_SZ + ((kk+1)&1)*WSLAB;
            for (int i = tid; i < WSLAB/16; i += 512)
                async_copy16(wdst + i*16, wsrc + i*16);
        }
        const int kh = kk / 3, kw = kk % 3;
        const char* wbase = lds + PATCH_SZ + (kk&1)*WSLAB;
        bf16x8 af[4];
        #pragma unroll
        for (int cf = 0; cf < 4; ++cf)
            af[cf] = ld_frag8(wbase + (wc*64 + cf*16 + l15)*88 + lj*16);
        #pragma unroll
        for (int nf = 0; nf < 8; ++nf) {
            const int cell = (wn + kh)*130 + nf*16 + l15 + kw;
            const bf16x8 bfr = ld_frag8(lds + cell*88 + lj*16);
            #pragma unroll
            for (int cf = 0; cf < 4; ++cf)
                acc[cf][nf] = __builtin_amdgcn_mfma_f32_16x16x32_bf16(
                    af[cf], bfr, acc[cf][nf], 0, 0, 0);
        }
        __syncthreads();
    }

    const float g0 = gammap[0];
    float* lf = (float*)lds;
    for (int k = 0; k < 4; ++k) {
        if (wc == k) {
            #pragma unroll
            for (int cf = 0; cf < 4; ++cf) {
                const int rl = cf*16 + 4*lj;
                #pragma unroll
                for (int nf = 0; nf < 8; ++nf) {
                    const int col = wn*128 + nf*16 + l15;
                    #pragma unroll
                    for (int j = 0; j < 4; ++j)
                        lf[(rl + j)*EPI_PITCH + col] = acc[cf][nf][j];
                }
            }
        }
        __syncthreads();
        #pragma unroll
        for (int it = 0; it < 8; ++it) {
            const int idx = tid + it*512;
            const int row = idx >> 6, c4 = idx & 63;
            const int co  = k*64 + row;
            const size_t g = ((size_t)b*CC + co)*NN + (size_t)h0*WW + c4*4;
            float4 v  = *(const float4*)(lf + row*EPI_PITCH + c4*4);
            float4 xv = *(const float4*)(x + g);
            float4 o;
            o.x = g0*gelu_fast(v.x) + xv.x;
            o.y = g0*gelu_fast(v.y) + xv.y;
            o.z = g0*gelu_fast(v.z) + xv.z;
            o.w = g0*gelu_fast(v.w) + xv.w;
            *(float4*)(out + g) = o;
        }
        __syncthreads();
    }
}

// ---------------------------------------------------------------------------
extern "C" void kernel_launch(void* const* d_in, const int* in_sizes, int n_in,
                              void* d_out, int out_size, void* d_ws, size_t ws_size,
                              hipStream_t stream)
{
    const float* x  = (const float*)d_in[0];
    const float* wq = (const float*)d_in[1];
    const float* bq = (const float*)d_in[2];
    const float* wk = (const float*)d_in[3];
    const float* bk = (const float*)d_in[4];
    const float* wv = (const float*)d_in[5];
    const float* bv = (const float*)d_in[6];
    const float* wp = (const float*)d_in[7];
    const float* gm = (const float*)d_in[8];
    float* out = (float*)d_out;

    // V scratch aliased into d_out (pv reads it before conv overwrites out).
    float* Vbuf = out;

    char* ws = (char*)d_ws;
    unsigned short* AOT  = (unsigned short*)ws;
    unsigned short* Wt   = (unsigned short*)(ws + AOT_ALLOC);
    unsigned short* Aswz = (unsigned short*)(ws + AOT_ALLOC + WT_BYTES);
    float* Ep  = (float*)(ws + AOT_ALLOC + WT_BYTES + ASWZ_BYTES);  // 2 MB
    float* ATT = Ep + (size_t)128*BB*1024;

    prep_kernel    <<<dim3(1024), 256, 0, stream>>>(wp, Wt, wq, wk, wv, Aswz, AOT);
    qkv_mfma_kernel<<<dim3(128, BB), 256, 0, stream>>>(x, Aswz, bq, bk, bv, Vbuf, Ep);
    softmax_kernel <<<dim3(BB), dim3(32, 32), 0, stream>>>(Ep, ATT);
    pv_kernel      <<<dim3(128, BB), 256, 0, stream>>>(Vbuf, ATT, AOT);
    conv_kernel    <<<dim3(64, BB), 512, 0, stream>>>(AOT, Wt, gm, x, out);
}